// Round 11
// baseline (203.044 us; speedup 1.0000x reference)
//
#include <hip/hip_runtime.h>
#include <hip/hip_bf16.h>

typedef short bf16x8 __attribute__((ext_vector_type(8)));
typedef float f32x4 __attribute__((ext_vector_type(4)));

static constexpr int M_DIM = 16384;
static constexpr int N_DIM = 4096;
static constexpr int K_DIM = 1024;

static constexpr int CVT_BLOCKS = (M_DIM * K_DIM / 8) / 256;   // 8192
static constexpr int WT_BLOCKS  = N_DIM;                       // 4096

__device__ __forceinline__ unsigned short f2bf(float f) {
  union { float f; unsigned u; } v; v.f = f;
  unsigned r = v.u + 0x7FFFu + ((v.u >> 16) & 1u);
  return (unsigned short)(r >> 16);
}

// Fused prep (R7-proven structure). wT is now FRAGMENT-MAJOR:
// frag(n16 = n>>4, ks = k>>5) is 1 KB: lane = ((k>>3)&3)*16 + (n&15) holds
// shorts j = k&7. flat_short = (n16*32+ks)*512 + lane*8 + j.
__global__ __launch_bounds__(256) void prep_kernel(
    const float* __restrict__ x, const float* __restrict__ a,
    const float* __restrict__ b, const float* __restrict__ s,
    unsigned short* __restrict__ xb, unsigned short* __restrict__ wT) {
  __shared__ float as_eff[8][64];
  __shared__ float bl[8][16];
  const int tid = threadIdx.x;

  if (blockIdx.x < CVT_BLOCKS) {
    const int i = (blockIdx.x * 256 + tid) * 2;
    float4 v0 = reinterpret_cast<const float4*>(x)[i];
    float4 v1 = reinterpret_cast<const float4*>(x)[i + 1];
    ushort4 o0, o1;
    o0.x = f2bf(v0.x); o0.y = f2bf(v0.y); o0.z = f2bf(v0.z); o0.w = f2bf(v0.w);
    o1.x = f2bf(v1.x); o1.y = f2bf(v1.y); o1.z = f2bf(v1.z); o1.w = f2bf(v1.w);
    reinterpret_cast<ushort4*>(xb)[i] = o0;
    reinterpret_cast<ushort4*>(xb)[i + 1] = o1;
    return;
  }

  const int n = blockIdx.x - CVT_BLOCKS;   // w column 0..4095
  const int j = n >> 5, l = n & 31;

#pragma unroll
  for (int t = tid; t < 512; t += 256) {
    const int r = t >> 6, i = t & 63;
    as_eff[r][i] = a[(r * 64 + i) * 128 + j] * s[i * 128 + j];
  }
  if (tid < 128) {
    const int r = tid >> 4, kk = tid & 15;
    bl[r][kk] = b[(r * 16 + kk) * 32 + l];
  }
  __syncthreads();

  // thread covers k = 4*tid .. 4*tid+3
  const int i = tid >> 2;
  const int kk0 = (tid & 3) * 4;
  float o[4] = {0.f, 0.f, 0.f, 0.f};
#pragma unroll
  for (int r = 0; r < 8; ++r) {
    const float av = as_eff[r][i];
#pragma unroll
    for (int q = 0; q < 4; ++q)
      o[q] += av * bl[r][kk0 + q];
  }
  ushort4 w4;
  w4.x = f2bf(o[0]); w4.y = f2bf(o[1]); w4.z = f2bf(o[2]); w4.w = f2bf(o[3]);
  // fragment-major write: k = tid*4 -> ks = tid>>3, kg = (tid>>1)&3, j0 = (tid&1)*4
  const int n16 = n >> 4, frow = n & 15;
  const int ks = tid >> 3;
  const int kg = (tid >> 1) & 3;
  const int j0 = (tid & 1) * 4;
  const size_t flat = ((size_t)(n16 * 32 + ks) << 9) + (size_t)(kg * 16 + frow) * 8 + j0;
  *reinterpret_cast<ushort4*>(&wT[flat]) = w4;
}

// ---- 256x256 GEMM: A via LDS dbuf, B DIRECT global->reg (fragment-major) ----
// Why (R6-R10 invariant): LDS pipe (~2800 cyc/K-tile) + MFMA (~2480) ran
// SERIALLY at ~5780 cyc/K-tile under every sync schedule. Moving B to the
// vmem/L1 pipe cuts LDS to A-only (~1800 cyc) and lets pipes overlap.
// 512 threads = 8 waves (2M x 4N); wave out 128x64 = 8x4 frags of 16x16x32.
// LDS: Al[2][256x64] = 64 KiB. ONE barrier per K-tile.
// Vmcnt ledger/tile t: entering: [B(t):8]. Issue STGA(t+1):4, LDB(t+1):8 ->
// [B(t):8][A:4][B':8]. WAITV(12) = B(t) landed; WAITV(8) at publish = A landed,
// B(t+1) stays in flight. t=14 publish leaves [B15:8]; t=15: WAITV(0), no stage.
// B ring: static names bE/bO (rule #20), 2x-unrolled loop.

#define PH_BARRIER __builtin_amdgcn_s_barrier()
#define SCHED0     __builtin_amdgcn_sched_barrier(0)
#define WAITV(N)   do { asm volatile("s_waitcnt vmcnt(" #N ")" ::: "memory"); SCHED0; } while (0)
#define WAITL(N)   do { asm volatile("s_waitcnt lgkmcnt(" #N ")" ::: "memory"); SCHED0; } while (0)

__global__ __launch_bounds__(512, 2) void gemm_kernel(
    const unsigned short* __restrict__ A, const unsigned short* __restrict__ BT,
    const float* __restrict__ bias, float* __restrict__ C) {
  __shared__ __align__(16) unsigned short Al[2][16384];

  const int tid  = threadIdx.x;
  const int lane = tid & 63;
  const int wave = tid >> 6;
  const int wm = wave >> 2;
  const int wn = wave & 3;
  const int wr = wm * 128;
  const int wc = wn * 64;
  const int frow = lane & 15;
  const int kg = lane >> 4;
  const int swz0 = (kg * 16) ^ ((lane & 7) << 4);
  const int swz1 = (64 + kg * 16) ^ ((lane & 7) << 4);

  int bid = blockIdx.x;              // 1024 blocks = 64 groups x 16
  int gid = bid >> 4, lid = bid & 15;
  gid = ((gid & 7) << 3) | (gid >> 3);          // bijective, 64 % 8 == 0
  const int bm = (gid >> 2) * 4 + (lid >> 2);
  const int bn = (gid & 3) * 4 + (lid & 3);
  const int brow = bm * 256, bcol = bn * 256;

  const unsigned short* Abase = A + (size_t)brow * K_DIM;
  const int n160 = (bcol + wc) >> 4;            // wave's first B n16-tile

  const int srow = tid >> 3;
  const int scol = ((((tid & 7) << 4) ^ ((srow & 7) << 4)) >> 1);
  const int ldsu = __builtin_amdgcn_readfirstlane(wave * 512);   // shorts

#define STG(dst, q, k0) __builtin_amdgcn_global_load_lds( \
    (const __attribute__((address_space(1))) void*)(Abase + (size_t)((q)*64 + srow) * K_DIM + (k0) + scol), \
    (__attribute__((address_space(3))) void*)((dst) + (q)*4096 + ldsu), 16, 0, 0)

#define STGA(dst, k0) do { STG(dst, 0, k0); STG(dst, 1, k0); \
                           STG(dst, 2, k0); STG(dst, 3, k0); SCHED0; } while (0)

  // B fragment load: tile t2, slice sl -> ks = t2*2+sl
#define LDB(dst, t2) { _Pragma("unroll") for (int ni = 0; ni < 4; ++ni) { \
    _Pragma("unroll") for (int sl = 0; sl < 2; ++sl) \
      dst[ni][sl] = *(const bf16x8*)(BT + (((size_t)(n160 + ni) * 32 + (t2)*2 + sl) << 9) + lane * 8); } \
    SCHED0; }

#define LOAD_AH(P, h) { _Pragma("unroll") for (int mi = 0; mi < 4; ++mi) { \
    const char* p_ = (const char*)(P) + (wr + frow + ((h)*4 + mi) * 16) * 128; \
    aF[mi][0] = *(const bf16x8*)(p_ + swz0); aF[mi][1] = *(const bf16x8*)(p_ + swz1); } SCHED0; }

#define MFMA32(mbase, bC) do { __builtin_amdgcn_s_setprio(1); \
    _Pragma("unroll") for (int sl = 0; sl < 2; ++sl) \
    _Pragma("unroll") for (int mi = 0; mi < 4; ++mi) \
    _Pragma("unroll") for (int ni = 0; ni < 4; ++ni) \
      acc[(mbase)+mi][ni] = __builtin_amdgcn_mfma_f32_16x16x32_bf16( \
          aF[mi][sl], bC[ni][sl], acc[(mbase)+mi][ni], 0, 0, 0); \
    __builtin_amdgcn_s_setprio(0); } while (0)

  f32x4 acc[8][4] = {};
  bf16x8 aF[4][2], bE[4][2], bO[4][2];

  // prologue: A0 -> Al[0] (4 STG), B0 -> bE (8 loads). WAITV(8): A0 landed.
  STGA(Al[0], 0);
  LDB(bE, 0);
  WAITV(8);
  PH_BARRIER;

  unsigned short* a_rd = &Al[0][0]; unsigned short* a_st = &Al[1][0];

  // one K-tile; bC = consume ring slot (tile t), bN = load target (tile t+1)
#define TILE_BODY(t, bC, bN) { \
    const int k_ = (t) * 64; \
    if ((t) < 15) { STGA(a_st, k_ + 64); LDB(bN, (t) + 1); } \
    LOAD_AH(a_rd, 0); \
    if ((t) < 15) { WAITV(12); } else { WAITV(0); } \
    WAITL(0); \
    MFMA32(0, bC); \
    LOAD_AH(a_rd, 1); \
    WAITL(0); \
    MFMA32(4, bC); \
    if ((t) < 15) WAITV(8); \
    PH_BARRIER; \
    unsigned short* tp_ = a_rd; a_rd = a_st; a_st = tp_; }

#pragma unroll 1
  for (int i = 0; i < 8; ++i) {
    const int t0 = i * 2;
    TILE_BODY(t0,     bE, bO);
    TILE_BODY(t0 + 1, bO, bE);
  }

  // ---- epilogue: per-wave LDS transpose -> contiguous float4 stores ----
  __syncthreads();
  float* T = (float*)&Al[0][0];                 // 8 waves * 16*68 floats = 34816 B
  float* Tw = T + wave * (16 * 68);
  const int col4 = lane & 15;
  const int rsel = lane >> 4;
  float4 bv = *(const float4*)&bias[bcol + wc + col4 * 4];

#pragma unroll
  for (int mi = 0; mi < 8; ++mi) {
#pragma unroll
    for (int ni = 0; ni < 4; ++ni)
#pragma unroll
      for (int r = 0; r < 4; ++r)
        Tw[(kg * 4 + r) * 68 + ni * 16 + frow] = acc[mi][ni][r];
    WAITL(0);                                   // fence write->read (R2/R3 root cause)
#pragma unroll
    for (int rr = 0; rr < 4; ++rr) {
      float4 v = *(float4*)&Tw[(rr * 4 + rsel) * 68 + col4 * 4];
      v.x += bv.x; v.y += bv.y; v.z += bv.z; v.w += bv.w;
      *(float4*)&C[(size_t)(brow + wr + mi * 16 + rr * 4 + rsel) * N_DIM + bcol + wc + col4 * 4] = v;
    }
    WAITL(0);                                   // reads done before next overwrite
  }
}

extern "C" void kernel_launch(void* const* d_in, const int* in_sizes, int n_in,
                              void* d_out, int out_size, void* d_ws, size_t ws_size,
                              hipStream_t stream) {
  const float* x    = (const float*)d_in[0];
  const float* a    = (const float*)d_in[1];
  const float* b    = (const float*)d_in[2];
  const float* s    = (const float*)d_in[3];
  const float* bias = (const float*)d_in[4];
  float* out = (float*)d_out;

  unsigned short* xb = (unsigned short*)d_ws;
  unsigned short* wT = (unsigned short*)((char*)d_ws + (size_t)M_DIM * K_DIM * 2);

  prep_kernel<<<CVT_BLOCKS + WT_BLOCKS, 256, 0, stream>>>(x, a, b, s, xb, wT);
  gemm_kernel<<<(M_DIM / 256) * (N_DIM / 256), 512, 0, stream>>>(xb, wT, bias, out);
}

// Round 12
// 186.493 us; speedup vs baseline: 1.0887x; 1.0887x over previous
//
#include <hip/hip_runtime.h>
#include <hip/hip_bf16.h>

typedef short bf16x8 __attribute__((ext_vector_type(8)));
typedef float f32x4 __attribute__((ext_vector_type(4)));

static constexpr int M_DIM = 16384;
static constexpr int N_DIM = 4096;
static constexpr int K_DIM = 1024;

static constexpr int CVT_BLOCKS = (M_DIM * K_DIM / 8) / 256;   // 8192
static constexpr int WT_BLOCKS  = N_DIM;                       // 4096 (R7 proven)

__device__ __forceinline__ unsigned short f2bf(float f) {
  union { float f; unsigned u; } v; v.f = f;
  unsigned r = v.u + 0x7FFFu + ((v.u >> 16) & 1u);
  return (unsigned short)(r >> 16);
}

// R7-proven fused prep: cvt blocks vectorized; one block per w^T column.
__global__ __launch_bounds__(256) void prep_kernel(
    const float* __restrict__ x, const float* __restrict__ a,
    const float* __restrict__ b, const float* __restrict__ s,
    unsigned short* __restrict__ xb, unsigned short* __restrict__ wT) {
  __shared__ float as_eff[8][64];
  __shared__ float bl[8][16];
  const int tid = threadIdx.x;

  if (blockIdx.x < CVT_BLOCKS) {
    const int i = (blockIdx.x * 256 + tid) * 2;
    float4 v0 = reinterpret_cast<const float4*>(x)[i];
    float4 v1 = reinterpret_cast<const float4*>(x)[i + 1];
    ushort4 o0, o1;
    o0.x = f2bf(v0.x); o0.y = f2bf(v0.y); o0.z = f2bf(v0.z); o0.w = f2bf(v0.w);
    o1.x = f2bf(v1.x); o1.y = f2bf(v1.y); o1.z = f2bf(v1.z); o1.w = f2bf(v1.w);
    reinterpret_cast<ushort4*>(xb)[i] = o0;
    reinterpret_cast<ushort4*>(xb)[i + 1] = o1;
    return;
  }

  const int n = blockIdx.x - CVT_BLOCKS;
  const int j = n >> 5, l = n & 31;

#pragma unroll
  for (int t = tid; t < 512; t += 256) {
    const int r = t >> 6, i = t & 63;
    as_eff[r][i] = a[(r * 64 + i) * 128 + j] * s[i * 128 + j];
  }
  if (tid < 128) {
    const int r = tid >> 4, kk = tid & 15;
    bl[r][kk] = b[(r * 16 + kk) * 32 + l];
  }
  __syncthreads();

  const int i = tid >> 2;
  const int kk0 = (tid & 3) * 4;
  float o[4] = {0.f, 0.f, 0.f, 0.f};
#pragma unroll
  for (int r = 0; r < 8; ++r) {
    const float av = as_eff[r][i];
#pragma unroll
    for (int q = 0; q < 4; ++q)
      o[q] += av * bl[r][kk0 + q];
  }
  ushort4 w4;
  w4.x = f2bf(o[0]); w4.y = f2bf(o[1]); w4.z = f2bf(o[2]); w4.w = f2bf(o[3]);
  *reinterpret_cast<ushort4*>(&wT[(size_t)n * K_DIM + tid * 4]) = w4;
}

// ---- PERSISTENT 256-block GEMM: 4 output tiles/block, pipeline never drains ----
// C(M,N) = A(M,K) * BT(N,K)^T + bias ; A,BT bf16, C f32.
// K-loop = R6-proven 2-barrier body. grid=256 (1 block/CU). Block p: bm=p&63
// (A-panel; all 4 blocks sharing it land on XCD bm%8 -> L2 reuse), bn=(p>>6)*4+jj.
// jj-boundary: [final barrier] -> issue 12-load prologue for jj+1 -> epilogue
// (scratch=Al[1], slab 16x64 = 32KB exact; Al[0]/Bl[0]/Bl[1] are prologue
// targets) -> next K-loop entry WAITV(36) (queue [B0:4][A0:4][B1:4][st:32],
// drains oldest 8, leaves B1+stores; stores L2-ack during tile 0). Tile-0
// publish WAITV(4) is newest-side invariant (always leaves exactly B2:4).

#define PH_BARRIER __builtin_amdgcn_s_barrier()
#define SCHED0     __builtin_amdgcn_sched_barrier(0)
#define WAITV(N)   do { asm volatile("s_waitcnt vmcnt(" #N ")" ::: "memory"); SCHED0; } while (0)
#define WAITL(N)   do { asm volatile("s_waitcnt lgkmcnt(" #N ")" ::: "memory"); SCHED0; } while (0)

__device__ __forceinline__ void quad_mfma(f32x4 (&acc)[8][4], const bf16x8 (&aH)[4][2],
                                          const bf16x8 (&bH)[2][2], int mbase, int nbase) {
  __builtin_amdgcn_s_setprio(1);
#pragma unroll
  for (int ks = 0; ks < 2; ++ks)
#pragma unroll
    for (int mi = 0; mi < 4; ++mi)
#pragma unroll
      for (int ni = 0; ni < 2; ++ni)
        acc[mbase + mi][nbase + ni] = __builtin_amdgcn_mfma_f32_16x16x32_bf16(
            aH[mi][ks], bH[ni][ks], acc[mbase + mi][nbase + ni], 0, 0, 0);
  __builtin_amdgcn_s_setprio(0);
}

__global__ __launch_bounds__(512, 2) void gemm_kernel(
    const unsigned short* __restrict__ A, const unsigned short* __restrict__ BT,
    const float* __restrict__ bias, float* __restrict__ C) {
  __shared__ __align__(16) unsigned short Al[2][16384];
  __shared__ __align__(16) unsigned short Bl[2][16384];

  const int tid  = threadIdx.x;
  const int lane = tid & 63;
  const int wave = tid >> 6;
  const int wm = wave >> 2;
  const int wn = wave & 3;
  const int wr = wm * 128;
  const int wc = wn * 64;
  const int frow = lane & 15;
  const int kg = lane >> 4;
  const int swz0 = (kg * 16) ^ ((lane & 7) << 4);
  const int swz1 = (64 + kg * 16) ^ ((lane & 7) << 4);

  const int p = blockIdx.x;          // 256 blocks
  const int bm = p & 63;
  const int bng = p >> 6;            // 0..3
  const int brow = bm * 256;

  const unsigned short* Abase = A + (size_t)brow * K_DIM;

  const int srow = tid >> 3;
  const int scol = ((((tid & 7) << 4) ^ ((srow & 7) << 4)) >> 1);
  const int ldsu = __builtin_amdgcn_readfirstlane(wave * 512);   // shorts

#define STG(dst, base, q, k0) __builtin_amdgcn_global_load_lds( \
    (const __attribute__((address_space(1))) void*)((base) + (size_t)((q)*64 + srow) * K_DIM + (k0) + scol), \
    (__attribute__((address_space(3))) void*)((dst) + (q)*4096 + ldsu), 16, 0, 0)

#define STG4(dst, base, k0) do { STG(dst, base, 0, k0); STG(dst, base, 1, k0); \
                                 STG(dst, base, 2, k0); STG(dst, base, 3, k0); } while (0)

#define LOAD_AH(P, h) { _Pragma("unroll") for (int mi = 0; mi < 4; ++mi) { \
    const char* p_ = (const char*)(P) + (wr + frow + ((h)*4 + mi) * 16) * 128; \
    aF[mi][0] = *(const bf16x8*)(p_ + swz0); aF[mi][1] = *(const bf16x8*)(p_ + swz1); } }

#define LOAD_BH(P, h, dst) { _Pragma("unroll") for (int ni = 0; ni < 2; ++ni) { \
    const char* p_ = (const char*)(P) + (wc + frow + ((h)*2 + ni) * 16) * 128; \
    dst[ni][0] = *(const bf16x8*)(p_ + swz0); dst[ni][1] = *(const bf16x8*)(p_ + swz1); } }

  // R6-proven K-tile body (2 barriers, counted lgkm, counted vmcnt publish)
#define TILE(PA, PB, SA, SB, VM) \
  LOAD_AH(PA, 0); SCHED0; \
  LOAD_BH(PB, 0, b0); SCHED0; \
  LOAD_BH(PB, 1, b1); SCHED0; \
  SA; \
  WAITL(4); \
  quad_mfma(acc, aF, b0, 0, 0); \
  WAITL(0); \
  quad_mfma(acc, aF, b1, 0, 2); \
  LOAD_AH(PA, 1); SCHED0; \
  WAITL(0); \
  quad_mfma(acc, aF, b1, 4, 2); \
  PH_BARRIER; \
  SB; \
  quad_mfma(acc, aF, b0, 4, 0); \
  VM; \
  PH_BARRIER;

  const int col4 = lane & 15;
  const int rsel = lane >> 4;
  float* Tw = (float*)&Al[1][0] + wave * 1024;   // 16x64 slab, 8 waves = 32KB exact

#pragma unroll 1
  for (int jj = 0; jj < 4; ++jj) {
    const int bcol = (bng * 4 + jj) * 256;
    const unsigned short* Bbase = BT + (size_t)bcol * K_DIM;

    if (jj == 0) {
      // cold prologue: B0+A0 (buf0) + B1 (buf1); leave B1 in flight
      STG4(Bl[0], Bbase, 0);
      STG4(Al[0], Abase, 0);
      STG4(Bl[1], Bbase, 64);
      WAITV(4);
    } else {
      // warm entry: queue [B0:4][A0:4][B1:4][st:32] -> drain oldest 8
      WAITV(36);
    }
    PH_BARRIER;

    f32x4 acc[8][4] = {};
    bf16x8 aF[4][2], b0[2][2], b1[2][2];

    int k = 0;
#pragma unroll 1
    for (int i = 0; i < 7; ++i) {
      TILE(Al[0], Bl[0], STG4(Al[1], Abase, k + 64), STG4(Bl[0], Bbase, k + 128), WAITV(4));
      TILE(Al[1], Bl[1], STG4(Al[0], Abase, k + 128), STG4(Bl[1], Bbase, k + 192), WAITV(4));
      k += 128;
    }
    TILE(Al[0], Bl[0], STG4(Al[1], Abase, k + 64), (void)0, WAITV(0));
    TILE(Al[1], Bl[1], (void)0, (void)0, WAITV(0));
    // all 4 LDS buffers free (reads drained before final barrier)

    // issue next tile's prologue FIRST (latency hides under epilogue)
    if (jj < 3) {
      const unsigned short* BbaseN = BT + (size_t)((bng * 4 + jj + 1) * 256) * K_DIM;
      STG4(Bl[0], BbaseN, 0);
      STG4(Al[0], Abase, 0);
      STG4(Bl[1], BbaseN, 64);
    }

    // epilogue: per-wave transpose via Al[1] scratch (16x64 slab) -> float4 stores
    float4 bv = *(const float4*)&bias[bcol + wc + col4 * 4];
#pragma unroll
    for (int mi = 0; mi < 8; ++mi) {
#pragma unroll
      for (int ni = 0; ni < 4; ++ni)
#pragma unroll
        for (int r = 0; r < 4; ++r)
          Tw[(kg * 4 + r) * 64 + ni * 16 + frow] = acc[mi][ni][r];
      WAITL(0);                                 // fence write->read
#pragma unroll
      for (int rr = 0; rr < 4; ++rr) {
        float4 v = *(float4*)&Tw[(rr * 4 + rsel) * 64 + col4 * 4];
        v.x += bv.x; v.y += bv.y; v.z += bv.z; v.w += bv.w;
        *(float4*)&C[(size_t)(brow + wr + mi * 16 + rr * 4 + rsel) * N_DIM + bcol + wc + col4 * 4] = v;
      }
      WAITL(0);                                 // reads done before next overwrite
    }
    // next iteration: WAITV(36) + barrier gates the staged buffers;
    // scratch (Al[1]) is restaged only at next K-loop's tile 0 (after barrier).
  }
}

extern "C" void kernel_launch(void* const* d_in, const int* in_sizes, int n_in,
                              void* d_out, int out_size, void* d_ws, size_t ws_size,
                              hipStream_t stream) {
  const float* x    = (const float*)d_in[0];
  const float* a    = (const float*)d_in[1];
  const float* b    = (const float*)d_in[2];
  const float* s    = (const float*)d_in[3];
  const float* bias = (const float*)d_in[4];
  float* out = (float*)d_out;

  unsigned short* xb = (unsigned short*)d_ws;
  unsigned short* wT = (unsigned short*)((char*)d_ws + (size_t)M_DIM * K_DIM * 2);

  prep_kernel<<<CVT_BLOCKS + WT_BLOCKS, 256, 0, stream>>>(x, a, b, s, xb, wT);
  gemm_kernel<<<256, 512, 0, stream>>>(xb, wT, bias, out);
}

// Round 13
// 183.727 us; speedup vs baseline: 1.1051x; 1.0151x over previous
//
#include <hip/hip_runtime.h>
#include <hip/hip_bf16.h>

typedef short bf16x8 __attribute__((ext_vector_type(8)));
typedef float f32x4 __attribute__((ext_vector_type(4)));

static constexpr int M_DIM = 16384;
static constexpr int N_DIM = 4096;
static constexpr int K_DIM = 1024;

static constexpr int CVT_BLOCKS = (M_DIM * K_DIM / 8) / 256;   // 8192
static constexpr int WT_BLOCKS  = N_DIM;                       // 4096 (R7 proven)

__device__ __forceinline__ unsigned short f2bf(float f) {
  union { float f; unsigned u; } v; v.f = f;
  unsigned r = v.u + 0x7FFFu + ((v.u >> 16) & 1u);
  return (unsigned short)(r >> 16);
}

// R7-proven fused prep: cvt blocks vectorized; one block per w^T column.
__global__ __launch_bounds__(256) void prep_kernel(
    const float* __restrict__ x, const float* __restrict__ a,
    const float* __restrict__ b, const float* __restrict__ s,
    unsigned short* __restrict__ xb, unsigned short* __restrict__ wT) {
  __shared__ float as_eff[8][64];
  __shared__ float bl[8][16];
  const int tid = threadIdx.x;

  if (blockIdx.x < CVT_BLOCKS) {
    const int i = (blockIdx.x * 256 + tid) * 2;
    float4 v0 = reinterpret_cast<const float4*>(x)[i];
    float4 v1 = reinterpret_cast<const float4*>(x)[i + 1];
    ushort4 o0, o1;
    o0.x = f2bf(v0.x); o0.y = f2bf(v0.y); o0.z = f2bf(v0.z); o0.w = f2bf(v0.w);
    o1.x = f2bf(v1.x); o1.y = f2bf(v1.y); o1.z = f2bf(v1.z); o1.w = f2bf(v1.w);
    reinterpret_cast<ushort4*>(xb)[i] = o0;
    reinterpret_cast<ushort4*>(xb)[i + 1] = o1;
    return;
  }

  const int n = blockIdx.x - CVT_BLOCKS;
  const int j = n >> 5, l = n & 31;

#pragma unroll
  for (int t = tid; t < 512; t += 256) {
    const int r = t >> 6, i = t & 63;
    as_eff[r][i] = a[(r * 64 + i) * 128 + j] * s[i * 128 + j];
  }
  if (tid < 128) {
    const int r = tid >> 4, kk = tid & 15;
    bl[r][kk] = b[(r * 16 + kk) * 32 + l];
  }
  __syncthreads();

  const int i = tid >> 2;
  const int kk0 = (tid & 3) * 4;
  float o[4] = {0.f, 0.f, 0.f, 0.f};
#pragma unroll
  for (int r = 0; r < 8; ++r) {
    const float av = as_eff[r][i];
#pragma unroll
    for (int q = 0; q < 4; ++q)
      o[q] += av * bl[r][kk0 + q];
  }
  ushort4 w4;
  w4.x = f2bf(o[0]); w4.y = f2bf(o[1]); w4.z = f2bf(o[2]); w4.w = f2bf(o[3]);
  *reinterpret_cast<ushort4*>(&wT[(size_t)n * K_DIM + tid * 4]) = w4;
}

// ---- 256x256 GEMM, WAR-free fragment registers (full-tile 24-read front) ----
// C(M,N) = A(M,K) * BT(N,K)^T + bias ; A,BT bf16, C f32.
// 512 threads = 8 waves (2M x 4N); wave out 128x64 = 8x4 frags of 16x16x32.
// LDS: Al[2]+Bl[2] = 128 KiB. 2 barriers/K-tile (R6 skeleton).
// THE FIX vs R4-R12 (all ~154us): those reused aF for both A-halves and
// b0/b1 across tiles -> every new ds_read had a WAR against the in-flight
// MFMA cluster -> reads serialized behind MFMA drain -> LDS+MFMA ran as a
// SUM (5775 cyc/K-tile). Here aF0,aF1,b0,b1 are all distinct, loaded in one
// 24-read burst (overlapping live ranges force distinct phys regs), consumed
// via counted lgkm. Next tile's writes hit registers whose consumers drained
// >=1 cluster + >=12-read lead earlier -> no WAR -> pipes overlap (max, not sum).
// Vmcnt ledger (R6-proven): publish queue [B(t+1):4][A(t+1):4][B(t+2):4] ->
// WAITV(4); t=14 -> WAITV(0); t=15 stages nothing.

#define PH_BARRIER __builtin_amdgcn_s_barrier()
#define SCHED0     __builtin_amdgcn_sched_barrier(0)
#define WAITV(N)   do { asm volatile("s_waitcnt vmcnt(" #N ")" ::: "memory"); SCHED0; } while (0)
#define WAITL(N)   do { asm volatile("s_waitcnt lgkmcnt(" #N ")" ::: "memory"); SCHED0; } while (0)

__device__ __forceinline__ void quad_mfma(f32x4 (&acc)[8][4], const bf16x8 (&aH)[4][2],
                                          const bf16x8 (&bH)[2][2], int mbase, int nbase) {
  __builtin_amdgcn_s_setprio(1);
#pragma unroll
  for (int ks = 0; ks < 2; ++ks)
#pragma unroll
    for (int mi = 0; mi < 4; ++mi)
#pragma unroll
      for (int ni = 0; ni < 2; ++ni)
        acc[mbase + mi][nbase + ni] = __builtin_amdgcn_mfma_f32_16x16x32_bf16(
            aH[mi][ks], bH[ni][ks], acc[mbase + mi][nbase + ni], 0, 0, 0);
  __builtin_amdgcn_s_setprio(0);
}

__global__ __launch_bounds__(512, 2) void gemm8_kernel(
    const unsigned short* __restrict__ A, const unsigned short* __restrict__ BT,
    const float* __restrict__ bias, float* __restrict__ C) {
  __shared__ __align__(16) unsigned short Al[2][16384];
  __shared__ __align__(16) unsigned short Bl[2][16384];

  const int tid  = threadIdx.x;
  const int lane = tid & 63;
  const int wave = tid >> 6;
  const int wm = wave >> 2;
  const int wn = wave & 3;
  const int wr = wm * 128;
  const int wc = wn * 64;
  const int frow = lane & 15;
  const int kg = lane >> 4;
  const int swz0 = (kg * 16) ^ ((lane & 7) << 4);
  const int swz1 = (64 + kg * 16) ^ ((lane & 7) << 4);

  int bid = blockIdx.x;              // 1024 blocks = 64 groups x 16
  int gid = bid >> 4, lid = bid & 15;
  gid = ((gid & 7) << 3) | (gid >> 3);          // bijective, 64 % 8 == 0
  const int bm = (gid >> 2) * 4 + (lid >> 2);
  const int bn = (gid & 3) * 4 + (lid & 3);
  const int brow = bm * 256, bcol = bn * 256;

  const unsigned short* Abase = A + (size_t)brow * K_DIM;
  const unsigned short* Bbase = BT + (size_t)bcol * K_DIM;

  const int srow = tid >> 3;
  const int scol = ((((tid & 7) << 4) ^ ((srow & 7) << 4)) >> 1);
  const int ldsu = __builtin_amdgcn_readfirstlane(wave * 512);   // shorts

#define STG(dst, base, q, k0) __builtin_amdgcn_global_load_lds( \
    (const __attribute__((address_space(1))) void*)((base) + (size_t)((q)*64 + srow) * K_DIM + (k0) + scol), \
    (__attribute__((address_space(3))) void*)((dst) + (q)*4096 + ldsu), 16, 0, 0)

#define STG4(dst, base, k0) do { STG(dst, base, 0, k0); STG(dst, base, 1, k0); \
                                 STG(dst, base, 2, k0); STG(dst, base, 3, k0); } while (0)

#define LOAD_AH(P, h, dst) { _Pragma("unroll") for (int mi = 0; mi < 4; ++mi) { \
    const char* p_ = (const char*)(P) + (wr + frow + ((h)*4 + mi) * 16) * 128; \
    dst[mi][0] = *(const bf16x8*)(p_ + swz0); dst[mi][1] = *(const bf16x8*)(p_ + swz1); } }

#define LOAD_BH(P, h, dst) { _Pragma("unroll") for (int ni = 0; ni < 2; ++ni) { \
    const char* p_ = (const char*)(P) + (wc + frow + ((h)*2 + ni) * 16) * 128; \
    dst[ni][0] = *(const bf16x8*)(p_ + swz0); dst[ni][1] = *(const bf16x8*)(p_ + swz1); } }

  f32x4 acc[8][4] = {};
  bf16x8 aF0[4][2], aF1[4][2], b0[2][2], b1[2][2];

  // prologue: B0+A0 (buf0) + B1 (buf1); WAITV(4) leaves B1 in flight.
  STG4(Bl[0], Bbase, 0);
  STG4(Al[0], Abase, 0);
  STG4(Bl[1], Bbase, 64);
  WAITV(4);
  PH_BARRIER;

  // K-tile body: 24-read front burst in pinned order aF0(8),b0(4),b1(4),aF1(8);
  // counted lgkm consumes; mid-barrier only for B-restage WAR (LDS side).
#define TILE(PA, PB, SA, SB, VM) \
  LOAD_AH(PA, 0, aF0); SCHED0; \
  LOAD_BH(PB, 0, b0);  SCHED0; \
  LOAD_BH(PB, 1, b1);  SCHED0; \
  LOAD_AH(PA, 1, aF1); SCHED0; \
  SA; \
  WAITL(12); \
  quad_mfma(acc, aF0, b0, 0, 0); \
  WAITL(8); \
  quad_mfma(acc, aF0, b1, 0, 2); \
  WAITL(0); \
  PH_BARRIER; \
  SB; \
  quad_mfma(acc, aF1, b0, 4, 0); \
  quad_mfma(acc, aF1, b1, 4, 2); \
  VM; \
  PH_BARRIER;

  int k = 0;
#pragma unroll 1
  for (int i = 0; i < 7; ++i) {
    // even tile E=k (buf0): SA stages A(k+64)->Al[1]; SB stages B(k+128)->Bl[0]
    TILE(Al[0], Bl[0], STG4(Al[1], Abase, k + 64), STG4(Bl[0], Bbase, k + 128), WAITV(4));
    // odd tile O=k+64 (buf1): SA stages A(k+128)->Al[0]; SB stages B(k+192)->Bl[1]
    TILE(Al[1], Bl[1], STG4(Al[0], Abase, k + 128), STG4(Bl[1], Bbase, k + 192), WAITV(4));
    k += 128;
  }
  // k = 896: T14 stages only A15; T15 stages nothing
  TILE(Al[0], Bl[0], STG4(Al[1], Abase, k + 64), (void)0, WAITV(0));
  TILE(Al[1], Bl[1], (void)0, (void)0, WAITV(0));

  // ---- epilogue: per-wave LDS transpose -> contiguous float4 stores ----
  __syncthreads();
  float* T = (float*)&Al[0][0];                 // 8 waves * 16*68 floats = 34816 B
  float* Tw = T + wave * (16 * 68);
  const int col4 = lane & 15;
  const int rsel = lane >> 4;
  float4 bv = *(const float4*)&bias[bcol + wc + col4 * 4];

#pragma unroll
  for (int mi = 0; mi < 8; ++mi) {
#pragma unroll
    for (int ni = 0; ni < 4; ++ni)
#pragma unroll
      for (int r = 0; r < 4; ++r)
        Tw[(kg * 4 + r) * 68 + ni * 16 + frow] = acc[mi][ni][r];
    WAITL(0);                                   // fence write->read (R2/R3 root cause)
#pragma unroll
    for (int rr = 0; rr < 4; ++rr) {
      float4 v = *(float4*)&Tw[(rr * 4 + rsel) * 68 + col4 * 4];
      v.x += bv.x; v.y += bv.y; v.z += bv.z; v.w += bv.w;
      *(float4*)&C[(size_t)(brow + wr + mi * 16 + rr * 4 + rsel) * N_DIM + bcol + wc + col4 * 4] = v;
    }
    WAITL(0);                                   // reads done before next overwrite
  }
}

extern "C" void kernel_launch(void* const* d_in, const int* in_sizes, int n_in,
                              void* d_out, int out_size, void* d_ws, size_t ws_size,
                              hipStream_t stream) {
  const float* x    = (const float*)d_in[0];
  const float* a    = (const float*)d_in[1];
  const float* b    = (const float*)d_in[2];
  const float* s    = (const float*)d_in[3];
  const float* bias = (const float*)d_in[4];
  float* out = (float*)d_out;

  unsigned short* xb = (unsigned short*)d_ws;
  unsigned short* wT = (unsigned short*)((char*)d_ws + (size_t)M_DIM * K_DIM * 2);

  prep_kernel<<<CVT_BLOCKS + WT_BLOCKS, 256, 0, stream>>>(x, a, b, s, xb, wT);
  gemm8_kernel<<<(M_DIM / 256) * (N_DIM / 256), 512, 0, stream>>>(xb, wT, bias, out);
}